// Round 4
// baseline (193.863 us; speedup 1.0000x reference)
//
#include <hip/hip_runtime.h>
#include <hip/hip_bf16.h>

// Problem constants
#define QSTRIDE 147584   // per-sample question_rep stride (128*128*9 + 128)
#define WOFF    147456   // bias offset within question_rep row

typedef __attribute__((ext_vector_type(8))) short bf16x8;
typedef __attribute__((ext_vector_type(4))) float f32x4;

static __device__ __forceinline__ ushort f2bf(float f) {
  union { float f; unsigned u; } x; x.f = f;
  unsigned r = x.u + 0x7fffu + ((x.u >> 16) & 1u);  // RNE bf16 (finite inputs)
  return (ushort)(r >> 16);
}
static __device__ __forceinline__ unsigned pk2(ushort a, ushort b) {
  return (unsigned)a | ((unsigned)b << 16);
}
// async global->LDS DMA: 16B per active lane, lands at ldsbase + lane*16
static __device__ __forceinline__ void async16(const ushort* g, ushort* l) {
  __builtin_amdgcn_global_load_lds((const __attribute__((address_space(1))) void*)g,
                                   (__attribute__((address_space(3))) void*)l, 16, 0, 0);
}

// ---------------------------------------------------------------------------
// 1) question_rep weights -> wt2[b][tap][cq][o][ci32] bf16
//    v2: NO LDS, NO barriers. Each thread owns (o, cq, 4-ci group): reads its
//    36 floats as 9x float4 (a wave covers 9KB contiguous; L1 absorbs the
//    strided overlap), writes 9x 8B packed stores. Grid 1024, high occupancy,
//    9 independent loads in flight per lane -> latency-immune.
// ---------------------------------------------------------------------------
__global__ __launch_bounds__(256) void pack_w_kernel(const float* __restrict__ q,
                                                     ushort* __restrict__ wt2) {
  int b = blockIdx.x >> 4, og = blockIdx.x & 15;   // 16 o-groups of 8
  int t = threadIdx.x;
  int o_loc = t >> 5, cq = (t >> 3) & 3, q4 = t & 7;
  int o_full = og * 8 + o_loc;
  int ci = cq * 32 + q4 * 4;                       // 4 consecutive channels
  const float4* src = (const float4*)(q + (size_t)b * QSTRIDE
                                        + (size_t)o_full * 1152 + (size_t)ci * 9);
  float4 ff[9];
#pragma unroll
  for (int i = 0; i < 9; ++i) ff[i] = src[i];      // 36 floats: w[o][ci..ci+4][tap 0..9]
  const float* v = (const float*)ff;
  ushort* dd = wt2 + (size_t)b * 147456 + (size_t)cq * 4096 + o_full * 32 + q4 * 4;
#pragma unroll
  for (int tap = 0; tap < 9; ++tap) {
    uint2 pkv;
    pkv.x = pk2(f2bf(v[tap]),      f2bf(v[9 + tap]));    // {ci, ci+1}
    pkv.y = pk2(f2bf(v[18 + tap]), f2bf(v[27 + tap]));   // {ci+2, ci+3}
    *(uint2*)(dd + (size_t)tap * 16384) = pkv;
  }
}

// ---------------------------------------------------------------------------
// 2) proj_w (128x256 fp32) -> pwb2[cq][o][c32] bf16 (chunk-major, frag-exact)
// ---------------------------------------------------------------------------
__global__ __launch_bounds__(256) void pack_pw_kernel(const float* __restrict__ pw,
                                                      ushort* __restrict__ pwb2) {
  int tg = blockIdx.x * 256 + threadIdx.x;   // 4096 threads
  int o  = tg >> 5;
  int c0 = (tg & 31) * 8;
  const float4* s4 = (const float4*)(pw + (size_t)o * 256 + c0);
  float4 f0 = s4[0], f1 = s4[1];
  uint4 pkv;
  pkv.x = pk2(f2bf(f0.x), f2bf(f0.y)); pkv.y = pk2(f2bf(f0.z), f2bf(f0.w));
  pkv.z = pk2(f2bf(f1.x), f2bf(f1.y)); pkv.w = pk2(f2bf(f1.z), f2bf(f1.w));
  *(uint4*)(pwb2 + (size_t)(c0 >> 5) * 4096 + o * 32 + (c0 & 31)) = pkv;
}

// ---------------------------------------------------------------------------
// 3) zero the halo of xp2[b][cq][34][34][32]
// ---------------------------------------------------------------------------
__global__ __launch_bounds__(256) void zero_border_kernel(ushort* __restrict__ xp2) {
  int b = blockIdx.x, t = threadIdx.x;
  for (int idx = t; idx < 528; idx += 256) {
    int cq = idx / 132, r = idx - cq * 132;
    int hp, wp;
    if (r < 34)       { hp = 0;        wp = r; }
    else if (r < 68)  { hp = 33;       wp = r - 34; }
    else if (r < 100) { hp = r - 67;   wp = 0; }     // 1..32
    else              { hp = r - 99;   wp = 33; }    // 1..32
    uint4 z = {0u,0u,0u,0u};
    uint4* dst = (uint4*)(xp2 + (((size_t)b * 4 + cq) * 1156 + hp * 34 + wp) * 32);
#pragma unroll
    for (int i = 0; i < 4; ++i) dst[i] = z;
  }
}

// ---------------------------------------------------------------------------
// 4) Fused projection v2: ZERO LDS, ZERO barriers.
//    Wave owns 128o x 16px (acc[8]). B-fragment loaded DIRECTLY from NCHW
//    global (lane = px, k-octet = quad: 8 scalar fp32 loads, 4x64B segs/instr)
//    and packed to bf16 in registers. A-fragment loaded directly from pwb2
//    (64KB, L2-hot, layout is fragment-exact). Grid 1024 (64-px tiles),
//    4 blocks/CU -> 16 independent waves/CU, compiler pipelines freely.
// ---------------------------------------------------------------------------
__global__ __launch_bounds__(256, 4) void proj_kernel(const ushort* __restrict__ pwb2,
                                                      const float* __restrict__ lhs,
                                                      const float* __restrict__ rhs,
                                                      const float* __restrict__ pb,
                                                      ushort* __restrict__ xp2) {
  int b = blockIdx.y, p0 = blockIdx.x * 64;
  int t = threadIdx.x;
  int lane = t & 63, wv = t >> 6;
  int quad = lane >> 4, li = lane & 15;
  int px = p0 + wv * 16 + li;                 // this lane's pixel (B-frag col)
  f32x4 acc[8] = {};
  // per-lane channel base: channel = quad*8 + j  ->  + (chunk&3)*32 later
  const float* bl = lhs + (size_t)b * 131072 + (size_t)quad * 8192 + px;
  const float* br = rhs + (size_t)b * 131072 + (size_t)quad * 8192 + px;

#pragma unroll
  for (int c = 0; c < 8; ++c) {               // 8 chunks of 32 channels
    const float* s = (c < 4 ? bl : br) + (size_t)(c & 3) * 32768;
    float f[8];
#pragma unroll
    for (int j = 0; j < 8; ++j) f[j] = s[(size_t)j * 1024];
    union { uint4 u; bf16x8 v; } bu;
    bu.u.x = pk2(f2bf(f[0]), f2bf(f[1]));
    bu.u.y = pk2(f2bf(f[2]), f2bf(f[3]));
    bu.u.z = pk2(f2bf(f[4]), f2bf(f[5]));
    bu.u.w = pk2(f2bf(f[6]), f2bf(f[7]));
    bf16x8 bg = bu.v;
    const ushort* ap = pwb2 + (size_t)c * 4096 + li * 32 + quad * 8;
#pragma unroll
    for (int mi = 0; mi < 8; ++mi) {
      bf16x8 af = *(const bf16x8*)(ap + mi * 512);   // row = mi*16+li, k-oct = quad
      acc[mi] = __builtin_amdgcn_mfma_f32_16x16x32_bf16(af, bg, acc[mi], 0, 0, 0);
    }
  }

  ushort* xpb = xp2 + (size_t)b * 4 * 1156 * 32;
  int h = px >> 5, w = px & 31;
#pragma unroll
  for (int mi = 0; mi < 8; ++mi) {
    int o0 = mi * 16 + quad * 4;
    float4 bias = *(const float4*)(pb + o0);
    f32x4 a = acc[mi];
    uint2 pkv;
    pkv.x = pk2(f2bf(a.x + bias.x), f2bf(a.y + bias.y));
    pkv.y = pk2(f2bf(a.z + bias.z), f2bf(a.w + bias.w));
    ushort* dp = xpb + ((size_t)(o0 >> 5) * 1156 + (h + 1) * 34 + (w + 1)) * 32 + (o0 & 31);
    *(uint2*)dp = pkv;
  }
}

// ---------------------------------------------------------------------------
// 5) Conv implicit GEMM v2: A-LDS eliminated -> barriers drop 36 -> 4.
//    A-fragments load directly from wt2 global (fragment-exact layout;
//    2.3MB/XCD L2-hot via b=blk&63 swizzle, 8x reuse). B supertile keeps
//    LDS (9-tap reuse), double-buffered, staged once per cq; the tap loop
//    is barrier-free so the compiler pipelines af loads under MFMAs.
// ---------------------------------------------------------------------------
__global__ __launch_bounds__(256, 2) void conv_kernel(const ushort* __restrict__ wt2,
                                                      const ushort* __restrict__ xp2,
                                                      const float* __restrict__ q,
                                                      float* __restrict__ out) {
  __shared__ ushort Bs[2][6528];              // 2 x 13,056 B
  int blk = blockIdx.x;
  int b = blk & 63, tile = blk >> 6;
  int p0 = tile * 128, h0 = tile * 4;
  int t = threadIdx.x;
  int lane = t & 63, wv = t >> 6;
  int m0 = (wv & 1) * 64, n0 = (wv >> 1) * 64;
  int quad = lane >> 4, li = lane & 15;
  f32x4 acc[4][4] = {};
  const ushort* wtb = wt2 + (size_t)b * 147456;
  const ushort* xpb = xp2 + (size_t)b * 147968;   // 4*1156*32

  // stage B(cq) -> Bs[buf] : 816 16B-lines, 204/wave (3 full + 12-lane tail)
  auto stageB = [&](int cqi, int buf) {
    const ushort* bgp = xpb + (size_t)(cqi * 1156 + h0 * 34) * 32;
    int lb = wv * 204;
    async16(bgp + (size_t)(lb +       lane) * 8, &Bs[buf][0] + (lb      ) * 8);
    async16(bgp + (size_t)(lb +  64 + lane) * 8, &Bs[buf][0] + (lb +  64) * 8);
    async16(bgp + (size_t)(lb + 128 + lane) * 8, &Bs[buf][0] + (lb + 128) * 8);
    if (lane < 12)
      async16(bgp + (size_t)(lb + 192 + lane) * 8, &Bs[buf][0] + (lb + 192) * 8);
  };

  stageB(0, 0);                               // prologue

#pragma unroll
  for (int cq = 0; cq < 4; ++cq) {
    __syncthreads();                          // drains DMA; Bs[cq&1] visible;
                                              // prior cq's LDS reads complete
    if (cq < 3) stageB(cq + 1, (cq + 1) & 1); // 9 taps of latency cover
    const ushort* bsr = &Bs[cq & 1][0];
    const ushort* wcq = wtb + (size_t)cq * 4096;
#pragma unroll
    for (int tap = 0; tap < 9; ++tap) {
      const ushort* ar = wcq + (size_t)tap * 16384;   // slab (tap*4+cq)*4096
      int kh = tap / 3, kw = tap - kh * 3;
      bf16x8 af[4], bg[4];
#pragma unroll
      for (int mi = 0; mi < 4; ++mi)
        af[mi] = *(const bf16x8*)(ar + (m0 + mi*16 + li) * 32 + quad * 8);
#pragma unroll
      for (int ni = 0; ni < 4; ++ni) {
        int pl = n0 + ni*16 + li;
        int hh = pl >> 5, ww = pl & 31;
        bg[ni] = *(const bf16x8*)(bsr + ((hh + kh) * 34 + (ww + kw)) * 32 + quad * 8);
      }
#pragma unroll
      for (int mi = 0; mi < 4; ++mi)
#pragma unroll
        for (int ni = 0; ni < 4; ++ni)
          acc[mi][ni] = __builtin_amdgcn_mfma_f32_16x16x32_bf16(af[mi], bg[ni], acc[mi][ni], 0, 0, 0);
    }
  }

  const float* qb = q + (size_t)b * QSTRIDE + WOFF;
  float* ob = out + (size_t)b * 128 * 1024 + p0;
#pragma unroll
  for (int mi = 0; mi < 4; ++mi) {
    int o0 = m0 + mi*16 + quad*4;
    float4 bias = *(const float4*)(qb + o0);
#pragma unroll
    for (int ni = 0; ni < 4; ++ni) {
      int pl = n0 + ni*16 + li;
      float* dp = ob + (size_t)o0 * 1024 + pl;
      f32x4 a = acc[mi][ni];
      dp[0]    = a.x + bias.x;
      dp[1024] = a.y + bias.y;
      dp[2048] = a.z + bias.z;
      dp[3072] = a.w + bias.w;
    }
  }
}

extern "C" void kernel_launch(void* const* d_in, const int* in_sizes, int n_in,
                              void* d_out, int out_size, void* d_ws, size_t ws_size,
                              hipStream_t stream) {
  const float* q   = (const float*)d_in[0];
  const float* lhs = (const float*)d_in[1];
  const float* rhs = (const float*)d_in[2];
  const float* pw  = (const float*)d_in[3];
  const float* pb  = (const float*)d_in[4];
  float* out = (float*)d_out;

  // workspace layout (37,879,808 B total)
  char* ws = (char*)d_ws;
  ushort* wt2  = (ushort*)(ws);               // 18,874,368 B : wt2[b][tap][cq][o][32]
  ushort* pwb2 = (ushort*)(ws + 18874368);    //     65,536 B : pwb2[cq][o][32]
  ushort* xp2  = (ushort*)(ws + 18939904);    // 18,939,904 B : xp2[b][cq][34][34][32]

  pack_w_kernel     <<<1024, 256, 0, stream>>>(q, wt2);
  pack_pw_kernel    <<<16,   256, 0, stream>>>(pw, pwb2);
  zero_border_kernel<<<64,   256, 0, stream>>>(xp2);
  proj_kernel       <<<dim3(16, 64), 256, 0, stream>>>(pwb2, lhs, rhs, pb, xp2);
  conv_kernel       <<<512,  256, 0, stream>>>(wt2, xp2, q, out);
}

// Round 5
// 181.437 us; speedup vs baseline: 1.0685x; 1.0685x over previous
//
#include <hip/hip_runtime.h>
#include <hip/hip_bf16.h>

// Problem constants
#define QSTRIDE 147584   // per-sample question_rep stride (128*128*9 + 128)
#define WOFF    147456   // bias offset within question_rep row

typedef __attribute__((ext_vector_type(8))) short bf16x8;
typedef __attribute__((ext_vector_type(4))) float f32x4;

static __device__ __forceinline__ ushort f2bf(float f) {
  union { float f; unsigned u; } x; x.f = f;
  unsigned r = x.u + 0x7fffu + ((x.u >> 16) & 1u);  // RNE bf16 (finite inputs)
  return (ushort)(r >> 16);
}
static __device__ __forceinline__ unsigned pk2(ushort a, ushort b) {
  return (unsigned)a | ((unsigned)b << 16);
}

// ---------------------------------------------------------------------------
// 1) question_rep weights -> wt2[b][tap][cq][o][ci32] bf16
//    (round-3 v1: LDS-staged, coalesced 1KB/instr global reads)
// ---------------------------------------------------------------------------
__global__ __launch_bounds__(256) void pack_w_kernel(const float* __restrict__ q,
                                                     ushort* __restrict__ wt2) {
  __shared__ float Ls[4608];                 // 4 o's x 1152 floats
  int b = blockIdx.x >> 3, ogrp = blockIdx.x & 7;
  int t = threadIdx.x;
  const float* gbase = q + (size_t)b * QSTRIDE + (size_t)ogrp * 16 * 1152;
  ushort* dstb = wt2 + (size_t)b * 147456;
  int o_loc = t >> 6;                        // wave id = local o
  int ci    = (t & 63) * 2;                  // 2 channels per thread
  int cq    = ci >> 5, coff = ci & 31;
  for (int r = 0; r < 4; ++r) {
    __syncthreads();                         // previous round's LDS reads done
    const float* gs = gbase + r * 4608;
#pragma unroll
    for (int i = 0; i < 18; ++i) Ls[i * 256 + t] = gs[i * 256 + t];
    __syncthreads();
    int o_full = ogrp * 16 + r * 4 + o_loc;
    const float* v = Ls + o_loc * 1152 + ci * 9;   // 18 consecutive floats
    float a[18];
#pragma unroll
    for (int i = 0; i < 18; ++i) a[i] = v[i];
    ushort* dd = dstb + (size_t)cq * 4096 + o_full * 32 + coff;
#pragma unroll
    for (int tap = 0; tap < 9; ++tap) {
      unsigned pkv = pk2(f2bf(a[tap]), f2bf(a[9 + tap]));  // {ci, ci+1}
      *(unsigned*)(dd + (size_t)tap * 16384) = pkv;
    }
  }
}

// ---------------------------------------------------------------------------
// 2) proj_w (128x256 fp32) -> pwb2[chunk][o][c32] bf16 (chunk-major, frag-exact)
// ---------------------------------------------------------------------------
__global__ __launch_bounds__(256) void pack_pw_kernel(const float* __restrict__ pw,
                                                      ushort* __restrict__ pwb2) {
  int tg = blockIdx.x * 256 + threadIdx.x;   // 4096 threads
  int o  = tg >> 5;
  int c0 = (tg & 31) * 8;
  const float4* s4 = (const float4*)(pw + (size_t)o * 256 + c0);
  float4 f0 = s4[0], f1 = s4[1];
  uint4 pkv;
  pkv.x = pk2(f2bf(f0.x), f2bf(f0.y)); pkv.y = pk2(f2bf(f0.z), f2bf(f0.w));
  pkv.z = pk2(f2bf(f1.x), f2bf(f1.y)); pkv.w = pk2(f2bf(f1.z), f2bf(f1.w));
  *(uint4*)(pwb2 + (size_t)(c0 >> 5) * 4096 + o * 32 + (c0 & 31)) = pkv;
}

// ---------------------------------------------------------------------------
// 3) FUSED proj+conv. Per block (b, tile of 4 output rows):
//    phase 1: mini-proj GEMM (M=128 o, N=192 px = 6 rows x 32 w, K=256)
//             straight from lhs/rhs global + L2-hot pwb2 into LDS Bs
//             [4cq][6r][34px][32ch] bf16, halo rows/cols zeroed in LDS.
//             af reused across 3 n-tiles; acc[3][8] = 3 indep dep chains.
//    phase 2: 3x3 conv, 9-tap barrier-free loop; A-frags from L2-hot wt2
//             (slab shared by the 8 tile-blocks of this sample via blk&63).
//    xp2 intermediate (19MB write + 19MB read) eliminated entirely.
// ---------------------------------------------------------------------------
__global__ __launch_bounds__(256, 2) void fused_conv_kernel(const ushort* __restrict__ wt2,
                                                            const ushort* __restrict__ pwb2,
                                                            const float* __restrict__ lhs,
                                                            const float* __restrict__ rhs,
                                                            const float* __restrict__ pb,
                                                            const float* __restrict__ q,
                                                            float* __restrict__ out) {
  __shared__ ushort Bs[4][6][34][32];        // 52,224 B
  int blk = blockIdx.x;
  int b = blk & 63, tile = blk >> 6;
  int p0 = tile * 128, h0 = tile * 4;
  int t = threadIdx.x;
  int lane = t & 63, wv = t >> 6;
  int quad = lane >> 4, li = lane & 15;

  // ---- col-halo zero: px 0 and 33 of every (cq, row) ----
  if (t < 48) {
    int cq = t & 3, side = (t >> 2) & 1, rr = t >> 3;   // rr 0..5
    uint4* z4 = (uint4*)&Bs[cq][rr][side ? 33 : 0][0];
    uint4 z; z.x = z.y = z.z = z.w = 0u;
    z4[0] = z; z4[1] = z; z4[2] = z; z4[3] = z;
  }

  // ---- phase 1: mini-proj into Bs ----
  {
    // wave wv owns n-tiles nt = wv*3 + k (12 tiles of 16 px = 6 rows x 32 w)
    int rk[3], wk[3], hk[3]; bool lv[3];
#pragma unroll
    for (int k = 0; k < 3; ++k) {
      int nt = wv * 3 + k;
      rk[k] = nt >> 1;                       // Bs row 0..5
      wk[k] = (nt & 1) * 16;                 // w base 0 or 16
      hk[k] = h0 - 1 + rk[k];                // image row
      lv[k] = (hk[k] >= 0) && (hk[k] < 32);
    }
    f32x4 acc[3][8] = {};
#pragma unroll
    for (int c = 0; c < 8; ++c) {            // 8 chunks of 32 channels
      const float* basep = (c < 4 ? lhs : rhs) + (size_t)b * 131072
                         + (size_t)((c & 3) * 32 + quad * 8) * 1024;
      bf16x8 bg[3];
#pragma unroll
      for (int k = 0; k < 3; ++k) {
        union { uint4 u; bf16x8 v; } bu;
        if (lv[k]) {
          const float* s = basep + hk[k] * 32 + wk[k] + li;
          float f[8];
#pragma unroll
          for (int j = 0; j < 8; ++j) f[j] = s[(size_t)j * 1024];
          bu.u.x = pk2(f2bf(f[0]), f2bf(f[1]));
          bu.u.y = pk2(f2bf(f[2]), f2bf(f[3]));
          bu.u.z = pk2(f2bf(f[4]), f2bf(f[5]));
          bu.u.w = pk2(f2bf(f[6]), f2bf(f[7]));
        } else {
          bu.u.x = bu.u.y = bu.u.z = bu.u.w = 0u;
        }
        bg[k] = bu.v;
      }
      const ushort* ap = pwb2 + (size_t)c * 4096 + li * 32 + quad * 8;
#pragma unroll
      for (int mi = 0; mi < 8; ++mi) {
        bf16x8 af = *(const bf16x8*)(ap + mi * 512);   // reused for all 3 k
#pragma unroll
        for (int k = 0; k < 3; ++k)
          acc[k][mi] = __builtin_amdgcn_mfma_f32_16x16x32_bf16(af, bg[k], acc[k][mi], 0, 0, 0);
      }
    }
    // epilogue -> Bs (live rows: +bias; dead rows: zeros -- conv zero-padding)
#pragma unroll
    for (int k = 0; k < 3; ++k) {
#pragma unroll
      for (int mi = 0; mi < 8; ++mi) {
        int o0 = mi * 16 + quad * 4;
        uint2 pkv;
        if (lv[k]) {
          float4 bias = *(const float4*)(pb + o0);
          f32x4 a = acc[k][mi];
          pkv.x = pk2(f2bf(a.x + bias.x), f2bf(a.y + bias.y));
          pkv.y = pk2(f2bf(a.z + bias.z), f2bf(a.w + bias.w));
        } else {
          pkv.x = 0u; pkv.y = 0u;
        }
        *(uint2*)&Bs[o0 >> 5][rk[k]][wk[k] + li + 1][o0 & 31] = pkv;
      }
    }
  }
  __syncthreads();                           // Bs fully built & visible

  // ---- phase 2: 3x3 conv over Bs, A-frags from wt2 global (L2-hot) ----
  int m0 = (wv & 1) * 64, n0 = (wv >> 1) * 64;
  f32x4 acc2[4][4] = {};
  const ushort* wtb = wt2 + (size_t)b * 147456;
#pragma unroll
  for (int cq = 0; cq < 4; ++cq) {
    const ushort* wcq = wtb + (size_t)cq * 4096;
#pragma unroll
    for (int tap = 0; tap < 9; ++tap) {
      const ushort* ar = wcq + (size_t)tap * 16384;   // slab (tap*4+cq)*4096
      int kh = tap / 3, kw = tap - kh * 3;
      bf16x8 af[4], bg[4];
#pragma unroll
      for (int mi = 0; mi < 4; ++mi)
        af[mi] = *(const bf16x8*)(ar + (m0 + mi*16 + li) * 32 + quad * 8);
#pragma unroll
      for (int ni = 0; ni < 4; ++ni) {
        int pl = n0 + ni*16 + li;
        int hh = pl >> 5, ww = pl & 31;
        bg[ni] = *(const bf16x8*)&Bs[cq][hh + kh][ww + kw][quad * 8];
      }
#pragma unroll
      for (int mi = 0; mi < 4; ++mi)
#pragma unroll
        for (int ni = 0; ni < 4; ++ni)
          acc2[mi][ni] = __builtin_amdgcn_mfma_f32_16x16x32_bf16(af[mi], bg[ni], acc2[mi][ni], 0, 0, 0);
    }
  }

  const float* qb = q + (size_t)b * QSTRIDE + WOFF;
  float* ob = out + (size_t)b * 128 * 1024 + p0;
#pragma unroll
  for (int mi = 0; mi < 4; ++mi) {
    int o0 = m0 + mi*16 + quad*4;
    float4 bias = *(const float4*)(qb + o0);
#pragma unroll
    for (int ni = 0; ni < 4; ++ni) {
      int pl = n0 + ni*16 + li;
      float* dp = ob + (size_t)o0 * 1024 + pl;
      f32x4 a = acc2[mi][ni];
      dp[0]    = a.x + bias.x;
      dp[1024] = a.y + bias.y;
      dp[2048] = a.z + bias.z;
      dp[3072] = a.w + bias.w;
    }
  }
}

extern "C" void kernel_launch(void* const* d_in, const int* in_sizes, int n_in,
                              void* d_out, int out_size, void* d_ws, size_t ws_size,
                              hipStream_t stream) {
  const float* q   = (const float*)d_in[0];
  const float* lhs = (const float*)d_in[1];
  const float* rhs = (const float*)d_in[2];
  const float* pw  = (const float*)d_in[3];
  const float* pb  = (const float*)d_in[4];
  float* out = (float*)d_out;

  // workspace layout (18,939,904 B used; xp2 eliminated)
  char* ws = (char*)d_ws;
  ushort* wt2  = (ushort*)(ws);               // 18,874,368 B : wt2[b][tap][cq][o][32]
  ushort* pwb2 = (ushort*)(ws + 18874368);    //     65,536 B : pwb2[chunk][o][32]

  pack_w_kernel    <<<512, 256, 0, stream>>>(q, wt2);
  pack_pw_kernel   <<<16,  256, 0, stream>>>(pw, pwb2);
  fused_conv_kernel<<<512, 256, 0, stream>>>(wt2, pwb2, lhs, rhs, pb, q, out);
}